// Round 12
// baseline (268.533 us; speedup 1.0000x reference)
//
#include <hip/hip_runtime.h>

// Problem: B=2, T=4096, C=768, H=12, HD=64. Inputs f32, OUTPUT f32.
// R21: both GEMMs get the T2+T4 pair that R13->R14 proved must ship
// together: (a) XOR-swizzled LDS (pre-swizzled global src col, linear DMA
// dest, (l16&7)*8 XOR on reads) killing the 16-way ds_read_b128 conflict
// (R19 counters: 10.6M conflict cycles ~ 20% of gemm<0>); (b) 2-buffer
// counted pipeline, ONE barrier/K-step: stage k+1 before compute k,
// vmcnt(0)+s_barrier after — loads land under the compute phase instead
// of being drained at issue. gemm128 LDS 32->64KB (2 blk/CU; R14 showed
// pipeline > occupancy here), gemm_n64 24->48KB (3 blk/CU).
// attn_chunk byte-identical to R17/R20 (83.5us). Catalog basis: T2 null
// alone at 2-barrier (m230/m252: drain hides conflicts), pipeline null
// alone (conflicted reads become critical path) — pair or nothing.
// Retained: R20 prep, R20 gemm_n64 tiling, R17 attn (counted-vmcnt
// 3-buffer DMA pipeline, s_setprio, K/V XOR-swizzle, swapped QK^T +
// in-register cvt_pk P pack, MFMA ones-column l, no-max softmax, split-K
// chunking, V pre-transposed (d,t), Q pre-scaled by 0.125*log2e).

typedef unsigned short u16;
typedef unsigned int u32;
using bf16x8 = __attribute__((ext_vector_type(8))) short;
using f32x4  = __attribute__((ext_vector_type(4))) float;

__device__ __forceinline__ float bf2f(u16 u) {
  return __uint_as_float(((u32)u) << 16);
}
__device__ __forceinline__ u16 f2bf(float f) {
  u32 u = __float_as_uint(f);
  u += 0x7fffu + ((u >> 16) & 1u);   // RNE
  return (u16)(u >> 16);
}
__device__ __forceinline__ u32 cvtpk(float lo, float hi) {
  u32 r;
  asm("v_cvt_pk_bf16_f32 %0, %1, %2" : "=v"(r) : "v"(lo), "v"(hi));
  return r;
}
__device__ __forceinline__ void gload_lds16(const u16* g, u16* l) {
  __builtin_amdgcn_global_load_lds(
      (const __attribute__((address_space(1))) unsigned int*)g,
      (__attribute__((address_space(3))) unsigned int*)l, 16, 0, 0);
}

__global__ void fill_sentinel_f32(float* __restrict__ out, int n, float v) {
  const int i0 = blockIdx.x * blockDim.x + threadIdx.x;
  const int stride = gridDim.x * blockDim.x;
  for (int i = i0; i < n; i += stride) out[i] = v;
}

// ------------------------------------------------- fused preprocessing
// blocks [0,1728): w_attn transpose; [1728,2304): w_proj transpose;
// [2304,3328): x f32->bf16 float4-vectorized; 3328: bias converts.
__global__ __launch_bounds__(256)
void prep(const float* __restrict__ x, const float* __restrict__ w_attn,
          const float* __restrict__ b_attn, const float* __restrict__ w_proj,
          const float* __restrict__ b_proj, u16* __restrict__ xb,
          u16* __restrict__ WtA, u16* __restrict__ WtP,
          u16* __restrict__ ba, u16* __restrict__ bp) {
  __shared__ u16 tile[32][33];
  const int bid = blockIdx.x, tid = threadIdx.x;
  if (bid < 2304) {
    const float* in; u16* out; int R, C, bx, by;
    if (bid < 1728) { in = w_attn; out = WtA; R = 768; C = 2304;
                      bx = bid % 72; by = bid / 72; }
    else            { in = w_proj; out = WtP; R = 768; C = 768;
                      bx = (bid - 1728) % 24; by = (bid - 1728) / 24; }
    const int c0 = bx * 32, r0 = by * 32;
    const int tx = tid & 31, ty = tid >> 5;
#pragma unroll
    for (int i = 0; i < 32; i += 8)
      tile[ty + i][tx] = f2bf(in[(size_t)(r0 + ty + i) * C + c0 + tx]);
    __syncthreads();
#pragma unroll
    for (int i = 0; i < 32; i += 8)
      out[(size_t)(c0 + ty + i) * R + r0 + tx] = tile[tx][ty + i];
  } else if (bid < 3328) {
    const int n4 = 8192 * 768 / 4;
    const int i0 = (bid - 2304) * 256 + tid, stride = 1024 * 256;
    const float4* src = (const float4*)x;
    ushort4* dst = (ushort4*)xb;
    for (int i = i0; i < n4; i += stride) {
      const float4 v = src[i];
      ushort4 o;
      o.x = f2bf(v.x); o.y = f2bf(v.y); o.z = f2bf(v.z); o.w = f2bf(v.w);
      dst[i] = o;
    }
  } else {
    for (int i = tid; i < 2304; i += 256) ba[i] = f2bf(b_attn[i]);
    for (int i = tid; i < 768; i += 256) bp[i] = f2bf(b_proj[i]);
  }
}

// ---------------------------------------------------------------- GEMM (MFMA)
#define QSCALE 0.18033688011112f   // 0.125 * log2(e)

// QKV projection. 128x128 tile; 2-buffer counted pipeline (1 barrier per
// K-step); XOR-swizzled LDS (inverse-swz global source, swz reads).
__global__ __launch_bounds__(256, 2)
void gemm128(const u16* __restrict__ A, const u16* __restrict__ Bt,
             const u16* __restrict__ bias, u16* __restrict__ O0,
             u16* __restrict__ O1, u16* __restrict__ O2, int Kd) {
  __shared__ __align__(16) u16 As[2][128 * 64];
  __shared__ __align__(16) u16 Bs[2][128 * 64];
  const int tid = threadIdx.x;
  const int lane = tid & 63, wave = tid >> 6;
  const int wm = wave >> 1, wn = wave & 1;
  const int l16 = lane & 15, quad = lane >> 4;
  const int swr = (l16 & 7) * 8;       // read-side XOR (elems)

  // staging: thread -> tile row rl (+32/round), granule m7; source col
  // pre-swizzled so linear DMA dest yields swizzled layout (rule #21).
  const int rl = tid >> 3, m7 = tid & 7;
  const int cs = (m7 ^ (rl & 7)) * 8;  // (row&7) invariant across +32 rounds
  const u16* Ag0 = A + (size_t)blockIdx.x * 128 * Kd + (size_t)rl * Kd + cs;
  const u16* Bg0 = Bt + (size_t)blockIdx.y * 128 * Kd + (size_t)rl * Kd + cs;
  const int ldsb = wave * 512;         // wave-uniform LDS base per round

  auto stage = [&](int bf, int kt) {
#pragma unroll
    for (int i = 0; i < 4; ++i) {      // 8 DMA: 4 rounds x (A,B)
      gload_lds16(Ag0 + (size_t)i * 32 * Kd + kt, &As[bf][i * 2048 + ldsb]);
      gload_lds16(Bg0 + (size_t)i * 32 * Kd + kt, &Bs[bf][i * 2048 + ldsb]);
    }
  };

  f32x4 acc[4][4] = {};
  stage(0, 0);
  asm volatile("s_waitcnt vmcnt(0)" ::: "memory");
  __builtin_amdgcn_sched_barrier(0);
  __builtin_amdgcn_s_barrier();
  int cur = 0;

  for (int kt = 0; kt < Kd; kt += 64) {
    const bool more = (kt + 64 < Kd);
    if (more) stage(cur ^ 1, kt + 64); // in flight across compute
    __builtin_amdgcn_sched_barrier(0);
#pragma unroll
    for (int s = 0; s < 2; ++s) {
      bf16x8 af[4], bfr[4];
#pragma unroll
      for (int i = 0; i < 4; ++i) {
        const int m = wm * 64 + i * 16 + l16;
        af[i] = *(const bf16x8*)&As[cur][m * 64 + (((s * 4 + quad) * 8) ^ swr)];
        const int n = wn * 64 + i * 16 + l16;
        bfr[i] = *(const bf16x8*)&Bs[cur][n * 64 + (((s * 4 + quad) * 8) ^ swr)];
      }
#pragma unroll
      for (int i = 0; i < 4; ++i)
#pragma unroll
        for (int j = 0; j < 4; ++j)
          acc[i][j] = __builtin_amdgcn_mfma_f32_16x16x32_bf16(af[i], bfr[j],
                                                              acc[i][j], 0, 0, 0);
    }
    if (more) {
      asm volatile("s_waitcnt vmcnt(0)" ::: "memory");   // k+1 landed (issued
      __builtin_amdgcn_sched_barrier(0);                 // one phase ago)
      __builtin_amdgcn_s_barrier();
      cur ^= 1;
    }
  }

#pragma unroll
  for (int i = 0; i < 4; ++i) {
    const int mbase = blockIdx.x * 128 + wm * 64 + i * 16 + quad * 4;
#pragma unroll
    for (int j = 0; j < 4; ++j) {
      const int nb = blockIdx.y * 128 + wn * 64 + j * 16;   // 16-aligned: never
      const int n = nb + l16;                               // crosses a 768 edge
      const float bv = bf2f(bias[n]);
      const int which = nb / 768;          // uniform per (block, wave, j)
      const int b = mbase >> 12, t = mbase & 4095;
      const int c = n - which * 768;
      const int h = c >> 6, d = c & 63;
      const size_t bh = (size_t)b * 12 + h;
      if (which == 0) {
#pragma unroll
        for (int r = 0; r < 4; ++r)
          O0[((bh * 4096 + t + r) << 6) + d] =
              f2bf((acc[i][j][r] + bv) * QSCALE);
      } else if (which == 1) {
#pragma unroll
        for (int r = 0; r < 4; ++r)
          O1[((bh * 4096 + t + r) << 6) + d] = f2bf(acc[i][j][r] + bv);
      } else {
        ushort4 pk;                        // V^T: 4 consecutive t -> one 8B store
        pk.x = f2bf(acc[i][j][0] + bv);
        pk.y = f2bf(acc[i][j][1] + bv);
        pk.z = f2bf(acc[i][j][2] + bv);
        pk.w = f2bf(acc[i][j][3] + bv);
        *(ushort4*)&O2[((bh << 6) + (size_t)d) * 4096 + t] = pk;
      }
    }
  }
}

// Output projection: 128(M) x 64(N) tile, grid (64,12) = 768 blocks.
// Same 2-buffer counted pipeline + swizzle. LDS 2x(16+8) = 48KB (3/CU).
__global__ __launch_bounds__(256, 3)
void gemm_n64(const u16* __restrict__ A, const u16* __restrict__ Bt,
              const u16* __restrict__ bias, float* __restrict__ out, int Kd) {
  __shared__ __align__(16) u16 As[2][128 * 64];
  __shared__ __align__(16) u16 Bs[2][64 * 64];
  const int tid = threadIdx.x;
  const int lane = tid & 63, wave = tid >> 6;
  const int l16 = lane & 15, quad = lane >> 4;
  const int swr = (l16 & 7) * 8;

  const int rl = tid >> 3, m7 = tid & 7;
  const int cs = (m7 ^ (rl & 7)) * 8;
  const u16* Ag0 = A + (size_t)blockIdx.x * 128 * Kd + (size_t)rl * Kd + cs;
  const u16* Bg0 = Bt + (size_t)blockIdx.y * 64 * Kd + (size_t)rl * Kd + cs;
  const int ldsb = wave * 512;

  auto stage = [&](int bf, int kt) {
#pragma unroll
    for (int i = 0; i < 4; ++i)
      gload_lds16(Ag0 + (size_t)i * 32 * Kd + kt, &As[bf][i * 2048 + ldsb]);
#pragma unroll
    for (int i = 0; i < 2; ++i)
      gload_lds16(Bg0 + (size_t)i * 32 * Kd + kt, &Bs[bf][i * 2048 + ldsb]);
  };

  f32x4 acc[2][4] = {};
  stage(0, 0);
  asm volatile("s_waitcnt vmcnt(0)" ::: "memory");
  __builtin_amdgcn_sched_barrier(0);
  __builtin_amdgcn_s_barrier();
  int cur = 0;

  for (int kt = 0; kt < Kd; kt += 64) {
    const bool more = (kt + 64 < Kd);
    if (more) stage(cur ^ 1, kt + 64);
    __builtin_amdgcn_sched_barrier(0);
#pragma unroll
    for (int s = 0; s < 2; ++s) {
      bf16x8 af[2], bfr[4];
#pragma unroll
      for (int i = 0; i < 2; ++i) {
        const int m = wave * 32 + i * 16 + l16;
        af[i] = *(const bf16x8*)&As[cur][m * 64 + (((s * 4 + quad) * 8) ^ swr)];
      }
#pragma unroll
      for (int j = 0; j < 4; ++j) {
        const int n = j * 16 + l16;
        bfr[j] = *(const bf16x8*)&Bs[cur][n * 64 + (((s * 4 + quad) * 8) ^ swr)];
      }
#pragma unroll
      for (int i = 0; i < 2; ++i)
#pragma unroll
        for (int j = 0; j < 4; ++j)
          acc[i][j] = __builtin_amdgcn_mfma_f32_16x16x32_bf16(af[i], bfr[j],
                                                              acc[i][j], 0, 0, 0);
    }
    if (more) {
      asm volatile("s_waitcnt vmcnt(0)" ::: "memory");
      __builtin_amdgcn_sched_barrier(0);
      __builtin_amdgcn_s_barrier();
      cur ^= 1;
    }
  }

#pragma unroll
  for (int i = 0; i < 2; ++i) {
    const int mbase = blockIdx.x * 128 + wave * 32 + i * 16 + quad * 4;
#pragma unroll
    for (int j = 0; j < 4; ++j) {
      const int n = blockIdx.y * 64 + j * 16 + l16;
      const float bv = bf2f(bias[n]);
#pragma unroll
      for (int r = 0; r < 4; ++r)
        out[(size_t)(mbase + r) * 768 + n] = acc[i][j][r] + bv;
    }
  }
}

// ---------------------------------------------------------------- attention
// Grid: 24 bh x 80 chunks = 1920 blocks. Chunk = (q-tile qt, j-th run of 16
// KV tiles). nc(qt)=ceil((qt+1)/8): qt<8 single-chunk -> direct Y write;
// else bf16 partial O + f32 partial l (additive; no-max softmax).
//
// LDS tiles are [64 rows][64 elems] LINEAR, data swizzled: element
// (row, c) of the logical tile lives at lds addr row*64 + (c ^ ((row&7)*8)).
// gload_lds writes base+lane*16 linearly; the per-lane GLOBAL src addr
// carries the inverse (same) XOR. All reads apply the XOR.
__global__ __launch_bounds__(256, 3)
void attn_chunk(const u16* __restrict__ Q, const u16* __restrict__ K,
                const u16* __restrict__ Vt, u16* __restrict__ Y,
                u16* __restrict__ part_o, float* __restrict__ part_l) {
  const int idx = blockIdx.x;
  const int bh = idx % 24;               // XCD-pinned
  const int cid = 79 - (idx / 24);       // big q-tiles dispatch first
  int qt = 0, base = 0, nc = 1;
  for (int q = 0; q < 32; ++q) {         // decode cid -> (qt, j)
    const int c = (q >> 3) + 1;
    if (cid < base + c) { qt = q; nc = c; break; }
    base += c;
  }
  const int j = cid - base;
  const int Nt = 2 * qt + 2;
  const int kbeg = j * 16;
  const int kend = (kbeg + 16 < Nt) ? kbeg + 16 : Nt;
  const int q0 = qt * 128;
  const int b = bh / 12, h = bh % 12;
  const size_t ho = (size_t)bh * 4096 * 64;
  const u16* Qg = Q + ho + (size_t)q0 * 64;
  const u16* Kg = K + ho;
  const u16* Vg = Vt + ho;               // (64, 4096)

  __shared__ __align__(16) u16 Ks[3][64 * 64];
  __shared__ __align__(16) u16 Vs[3][64 * 64];

  const int tid = threadIdx.x;
  const int lane = tid & 63, wave = tid >> 6;
  const int l16 = lane & 15, quad = lane >> 4;
  const int sw8 = (l16 & 7) * 8;         // read-side XOR (elems)

  // staging geometry: thread covers logical tile row rl=tid>>3, granule m=tid&7
  const int rl = tid >> 3, m7 = tid & 7;
  const int cs = (m7 ^ (rl & 7)) * 8;    // pre-swizzled source column (elems)
  const u16* kg0 = Kg + (size_t)rl * 64 + cs;     // + kt2*4096
  const u16* vg0 = Vg + (size_t)rl * 4096 + cs;   // + kt2*64
  const int wb = wave * 512;             // per-wave LDS base (elems)

  bf16x8 qf[2][2];
#pragma unroll
  for (int rt = 0; rt < 2; ++rt)
#pragma unroll
    for (int s = 0; s < 2; ++s)
      qf[rt][s] = *(const bf16x8*)&Qg[(wave * 32 + rt * 16 + l16) * 64 + s * 32 + quad * 8];

  bf16x8 ones;
#pragma unroll
  for (int e = 0; e < 8; ++e) ones[e] = (short)0x3F80;   // bf16 1.0

  f32x4 lacc[2] = {};
  f32x4 o[2][4] = {};

  auto stage = [&](int bf, int kt2) {
    const size_t ko = (size_t)kt2 * 4096;   // kt2*64 rows * 64 elems
    const int to = kt2 * 64;
    gload_lds16(kg0 + ko,               &Ks[bf][wb]);
    gload_lds16(kg0 + ko + 2048,        &Ks[bf][2048 + wb]);        // rows +32
    gload_lds16(vg0 + to,               &Vs[bf][wb]);
    gload_lds16(vg0 + to + 32 * 4096,   &Vs[bf][2048 + wb]);        // d rows +32
  };

  // ---- prologue: depth-2 prefetch, counted wait for buffer 0 ----
  const int ntt = kend - kbeg;
  stage(0, kbeg);
  if (ntt > 1) {
    stage(1, kbeg + 1);
    asm volatile("s_waitcnt vmcnt(4)" ::: "memory");   // buf0's 4 landed
  } else {
    asm volatile("s_waitcnt vmcnt(0)" ::: "memory");
  }
  __builtin_amdgcn_sched_barrier(0);
  __builtin_amdgcn_s_barrier();
  int cur = 0;

  for (int kt2 = kbeg; kt2 < kend; ++kt2) {
    const int t0 = kt2 * 64;
    const bool pf = (kt2 + 2 < kend);
    if (pf) {                            // depth-2 prefetch into 3rd buffer
      int nb = cur + 2; if (nb >= 3) nb -= 3;
      stage(nb, kt2 + 2);
    }
    __builtin_amdgcn_sched_barrier(0);   // keep DMA issue ahead of compute

    // ---- S^T = K Q^T : 16 MFMA. sc[nt][rt]: row=t (quad*4+r), col=q (l16)
    f32x4 sc[4][2] = {};
#pragma unroll
    for (int s = 0; s < 2; ++s) {
      bf16x8 kf[4];
#pragma unroll
      for (int nt = 0; nt < 4; ++nt)
        kf[nt] = *(const bf16x8*)&Ks[cur][(nt * 16 + l16) * 64 +
                                          ((s * 32 + quad * 8) ^ sw8)];
      __builtin_amdgcn_s_setprio(1);
#pragma unroll
      for (int nt = 0; nt < 4; ++nt)
#pragma unroll
        for (int rt = 0; rt < 2; ++rt)
          sc[nt][rt] = __builtin_amdgcn_mfma_f32_16x16x32_bf16(kf[nt], qf[rt][s],
                                                               sc[nt][rt], 0, 0, 0);
      __builtin_amdgcn_s_setprio(0);
    }

    // ---- no-max softmax + in-register bf16 pack (l via PV ones-col) ----
    u32 pw[4][2][2];
#pragma unroll
    for (int rt = 0; rt < 2; ++rt) {
      const int rowb = q0 + wave * 32 + rt * 16;
      if (t0 + 63 <= rowb) {               // tile fully below diagonal
#pragma unroll
        for (int nt = 0; nt < 4; ++nt) {
          f32x4 p;
#pragma unroll
          for (int r = 0; r < 4; ++r)
            p[r] = __builtin_amdgcn_exp2f(sc[nt][rt][r]);
          pw[nt][rt][0] = cvtpk(p[0], p[1]);
          pw[nt][rt][1] = cvtpk(p[2], p[3]);
        }
      } else {
        const int qrow = rowb + l16;
#pragma unroll
        for (int nt = 0; nt < 4; ++nt) {
          f32x4 p;
#pragma unroll
          for (int r = 0; r < 4; ++r) {
            float pv = __builtin_amdgcn_exp2f(sc[nt][rt][r]);
            if (t0 + nt * 16 + quad * 4 + r > qrow) pv = 0.f;
            p[r] = pv;
          }
          pw[nt][rt][0] = cvtpk(p[0], p[1]);
          pw[nt][rt][1] = cvtpk(p[2], p[3]);
        }
      }
    }

    // ---- O += P V (+ l += P 1) : 20 MFMA, permuted k-slots both operands
#pragma unroll
    for (int s2 = 0; s2 < 2; ++s2) {
      bf16x8 vf[4];
#pragma unroll
      for (int dt = 0; dt < 4; ++dt) {
        const int vbase = (dt * 16 + l16) * 64;
        const int a1 = vbase + ((s2 * 32 + quad * 4) ^ sw8);
        union { uint2 hv[2]; bf16x8 v; } uv;
        uv.hv[0] = *(const uint2*)&Vs[cur][a1];        // t' = 32*s2+quad*4+0..3
        uv.hv[1] = *(const uint2*)&Vs[cur][a1 ^ 16];   // t' = +16
        vf[dt] = uv.v;
      }
#pragma unroll
      for (int rt = 0; rt < 2; ++rt) {
        union { u32 w[4]; bf16x8 v; } up;
        up.w[0] = pw[2 * s2][rt][0];
        up.w[1] = pw[2 * s2][rt][1];
        up.w[2] = pw[2 * s2 + 1][rt][0];
        up.w[3] = pw[2 * s2 + 1][rt][1];
        __builtin_amdgcn_s_setprio(1);
#pragma unroll
        for (int dt = 0; dt < 4; ++dt)
          o[rt][dt] = __builtin_amdgcn_mfma_f32_16x16x32_bf16(up.v, vf[dt],
                                                              o[rt][dt], 0, 0, 0);
        lacc[rt] = __builtin_amdgcn_mfma_f32_16x16x32_bf16(up.v, ones,
                                                           lacc[rt], 0, 0, 0);
        __builtin_amdgcn_s_setprio(0);
      }
    }

    if (kt2 + 1 < kend) {
      // counted wait: leave k+2's 4 DMAs in flight, require k+1's landed.
      if (pf) asm volatile("s_waitcnt vmcnt(4)" ::: "memory");
      else    asm volatile("s_waitcnt vmcnt(0)" ::: "memory");
      __builtin_amdgcn_sched_barrier(0);
      __builtin_amdgcn_s_barrier();
      if (++cur == 3) cur = 0;
    }
  }

  // lacc[rt][r] = l for q-row (quad*4+r), identical across lanes: no shuffles.
  if (nc == 1) {
    // direct: Y (b, t, h*64+d) bf16
#pragma unroll
    for (int rt = 0; rt < 2; ++rt)
#pragma unroll
      for (int r = 0; r < 4; ++r) {
        const float inv = 1.f / lacc[rt][r];
        const int t = q0 + wave * 32 + rt * 16 + quad * 4 + r;
#pragma unroll
        for (int dt = 0; dt < 4; ++dt)
          Y[((size_t)b * 4096 + t) * 768 + h * 64 + dt * 16 + l16] =
              f2bf(o[rt][dt][r] * inv);
      }
  } else {
    const int pslot = bh * 72 + (cid - 8);     // cids 8..79 are partial chunks
    u16* po = part_o + (size_t)pslot * 8192;   // [row 0..127][d 0..63]
    float* pl = part_l + pslot * 128;
#pragma unroll
    for (int rt = 0; rt < 2; ++rt)
#pragma unroll
      for (int r = 0; r < 4; ++r) {
        const int row = wave * 32 + rt * 16 + quad * 4 + r;
#pragma unroll
        for (int dt = 0; dt < 4; ++dt)
          po[row * 64 + dt * 16 + l16] = f2bf(o[rt][dt][r]);
        if (l16 == 0) pl[row] = lacc[rt][r];
      }
  }
}

// Combine partial chunks for qt >= 8.  Grid (24 bh, 24 qt-8).
__global__ __launch_bounds__(256, 8)
void attn_combine(const u16* __restrict__ part_o, const float* __restrict__ part_l,
                  u16* __restrict__ Y) {
  const int bh = blockIdx.x, qt = 8 + blockIdx.y;
  const int g = qt >> 3, i = qt & 7;
  const int nc = g + 1;
  const int base = 4 * g * (g + 1) + i * (g + 1);
  const int slot0 = bh * 72 + base - 8;
  const int b = bh / 12, h = bh % 12;
  const int q0 = qt * 128;
  for (int e = threadIdx.x; e < 8192; e += 256) {
    const int row = e >> 6, d = e & 63;
    float Os = 0.f, ls = 0.f;
    for (int c = 0; c < nc; ++c) {
      Os += bf2f(part_o[(size_t)(slot0 + c) * 8192 + e]);
      ls += part_l[(slot0 + c) * 128 + row];
    }
    Y[((size_t)b * 4096 + q0 + row) * 768 + h * 64 + d] = f2bf(Os / ls);
  }
}

// ---------------------------------------------------------------- launch
extern "C" void kernel_launch(void* const* d_in, const int* in_sizes, int n_in,
                              void* d_out, int out_size, void* d_ws, size_t ws_size,
                              hipStream_t stream) {
  (void)in_sizes; (void)n_in;
  const float* x      = (const float*)d_in[0];
  const float* w_attn = (const float*)d_in[1];
  const float* b_attn = (const float*)d_in[2];
  const float* w_proj = (const float*)d_in[3];
  const float* b_proj = (const float*)d_in[4];
  float* out = (float*)d_out;

  char* ws = (char*)d_ws;
  size_t off = 0;
  auto alloc = [&](size_t bytes) -> void* {
    void* p = ws + off;
    off += (bytes + 255) & ~(size_t)255;
    return p;
  };
  u16* xb  = (u16*)alloc((size_t)8192 * 768 * 2);
  u16* WtA = (u16*)alloc((size_t)2304 * 768 * 2);
  u16* WtP = (u16*)alloc((size_t)768 * 768 * 2);
  u16* ba  = (u16*)alloc(2304 * 2);
  u16* bp  = (u16*)alloc(768 * 2);
  u16* Q   = (u16*)alloc((size_t)6291456 * 2);   // (B,H,T,64), pre-scaled
  u16* Kp  = (u16*)alloc((size_t)6291456 * 2);   // (B,H,T,64)
  u16* Vt  = (u16*)alloc((size_t)6291456 * 2);   // (B,H,64,T)
  u16* Y   = (u16*)alloc((size_t)6291456 * 2);
  u16* part_o  = (u16*)alloc((size_t)24 * 72 * 8192 * 2);   // 28.3 MB
  float* part_l = (float*)alloc((size_t)24 * 72 * 128 * 4);

  if (ws_size < off) {   // decodable sentinel: absmax ~= 100 + ws_MB
    fill_sentinel_f32<<<256, 256, 0, stream>>>(out, out_size,
                                               100.0f + (float)(ws_size >> 20));
    return;
  }

  prep<<<3329, 256, 0, stream>>>(x, w_attn, b_attn, w_proj, b_proj,
                                 xb, WtA, WtP, ba, bp);
  gemm128<<<dim3(64, 18), 256, 0, stream>>>(xb, WtA, ba, Q, Kp, Vt, 768);
  attn_chunk<<<1920, 256, 0, stream>>>(Q, Kp, Vt, Y, part_o, part_l);
  attn_combine<<<dim3(24, 24), 256, 0, stream>>>(part_o, part_l, Y);
  gemm_n64<<<dim3(64, 12), 256, 0, stream>>>(Y, WtP, bp, out, 768);
}

// Round 13
// 230.580 us; speedup vs baseline: 1.1646x; 1.1646x over previous
//
#include <hip/hip_runtime.h>

// Problem: B=2, T=4096, C=768, H=12, HD=64. Inputs f32, OUTPUT f32.
// R22: R20-exact (best measured, 266.9us — R21's gemm T2+T4 pair was
// neutral, reverted) + ONE change: attn_combine vectorized. It read
// part_o with scalar 2B u16 loads inside a runtime nc-loop (G13 /
// Common-mistake #2): 576 blocks x 32 elems x nc serial 2B loads =
// latency-bound chain, est 15-25us for only ~38MB traffic. Now each
// thread combines 8 consecutive d via one uint4 (16B) load per chunk,
// 4 unrolled row-groups for ILP, 16B packed Y store.
// Retained: R20 prep, R20 single-buffer DMA gemm128 (128x128) and
// gemm_n64 (128x64, 768 blocks), R17 attn (counted-vmcnt 3-buffer DMA
// pipeline, s_setprio, K/V XOR-swizzle via pre-swizzled global source,
// swapped QK^T + in-register cvt_pk P pack, MFMA ones-column l, no-max
// softmax, split-K chunking, V pre-transposed (d,t), Q pre-scaled by
// 0.125*log2e).

typedef unsigned short u16;
typedef unsigned int u32;
using bf16x8 = __attribute__((ext_vector_type(8))) short;
using f32x4  = __attribute__((ext_vector_type(4))) float;

__device__ __forceinline__ float bf2f(u16 u) {
  return __uint_as_float(((u32)u) << 16);
}
__device__ __forceinline__ u16 f2bf(float f) {
  u32 u = __float_as_uint(f);
  u += 0x7fffu + ((u >> 16) & 1u);   // RNE
  return (u16)(u >> 16);
}
__device__ __forceinline__ u32 cvtpk(float lo, float hi) {
  u32 r;
  asm("v_cvt_pk_bf16_f32 %0, %1, %2" : "=v"(r) : "v"(lo), "v"(hi));
  return r;
}
__device__ __forceinline__ void gload_lds16(const u16* g, u16* l) {
  __builtin_amdgcn_global_load_lds(
      (const __attribute__((address_space(1))) unsigned int*)g,
      (__attribute__((address_space(3))) unsigned int*)l, 16, 0, 0);
}

__global__ void fill_sentinel_f32(float* __restrict__ out, int n, float v) {
  const int i0 = blockIdx.x * blockDim.x + threadIdx.x;
  const int stride = gridDim.x * blockDim.x;
  for (int i = i0; i < n; i += stride) out[i] = v;
}

// ------------------------------------------------- fused preprocessing
// blocks [0,1728): w_attn transpose; [1728,2304): w_proj transpose;
// [2304,3328): x f32->bf16 float4-vectorized; 3328: bias converts.
__global__ __launch_bounds__(256)
void prep(const float* __restrict__ x, const float* __restrict__ w_attn,
          const float* __restrict__ b_attn, const float* __restrict__ w_proj,
          const float* __restrict__ b_proj, u16* __restrict__ xb,
          u16* __restrict__ WtA, u16* __restrict__ WtP,
          u16* __restrict__ ba, u16* __restrict__ bp) {
  __shared__ u16 tile[32][33];
  const int bid = blockIdx.x, tid = threadIdx.x;
  if (bid < 2304) {
    const float* in; u16* out; int R, C, bx, by;
    if (bid < 1728) { in = w_attn; out = WtA; R = 768; C = 2304;
                      bx = bid % 72; by = bid / 72; }
    else            { in = w_proj; out = WtP; R = 768; C = 768;
                      bx = (bid - 1728) % 24; by = (bid - 1728) / 24; }
    const int c0 = bx * 32, r0 = by * 32;
    const int tx = tid & 31, ty = tid >> 5;
#pragma unroll
    for (int i = 0; i < 32; i += 8)
      tile[ty + i][tx] = f2bf(in[(size_t)(r0 + ty + i) * C + c0 + tx]);
    __syncthreads();
#pragma unroll
    for (int i = 0; i < 32; i += 8)
      out[(size_t)(c0 + ty + i) * R + r0 + tx] = tile[tx][ty + i];
  } else if (bid < 3328) {
    const int n4 = 8192 * 768 / 4;
    const int i0 = (bid - 2304) * 256 + tid, stride = 1024 * 256;
    const float4* src = (const float4*)x;
    ushort4* dst = (ushort4*)xb;
    for (int i = i0; i < n4; i += stride) {
      const float4 v = src[i];
      ushort4 o;
      o.x = f2bf(v.x); o.y = f2bf(v.y); o.z = f2bf(v.z); o.w = f2bf(v.w);
      dst[i] = o;
    }
  } else {
    for (int i = tid; i < 2304; i += 256) ba[i] = f2bf(b_attn[i]);
    for (int i = tid; i < 768; i += 256) bp[i] = f2bf(b_proj[i]);
  }
}

// ---------------------------------------------------------------- GEMM (MFMA)
#define QSCALE 0.18033688011112f   // 0.125 * log2(e)

// m97 structure: DMA staging, linear [128][64] LDS, 2-barrier K-loop.
// Used for the QKV projection (bf16 A = xb).
__global__ __launch_bounds__(256, 3)
void gemm128(const u16* __restrict__ A, const u16* __restrict__ Bt,
             const u16* __restrict__ bias, u16* __restrict__ O0,
             u16* __restrict__ O1, u16* __restrict__ O2, int Kd) {
  __shared__ __align__(16) u16 As[128 * 64];
  __shared__ __align__(16) u16 Bs[128 * 64];
  const int tid = threadIdx.x;
  const int lane = tid & 63, wave = tid >> 6;
  const int wm = wave >> 1, wn = wave & 1;
  const int l16 = lane & 15, quad = lane >> 4;

  const u16* Ag0 = A + (size_t)blockIdx.x * 128 * Kd +
                   (size_t)(tid >> 3) * Kd + (tid & 7) * 8;
  const u16* Bg0 = Bt + (size_t)blockIdx.y * 128 * Kd +
                   (size_t)(tid >> 3) * Kd + (tid & 7) * 8;
  const int ldsb = wave * 512;   // wave-uniform LDS base (elems) per round

  f32x4 acc[4][4] = {};
  for (int kt = 0; kt < Kd; kt += 64) {
#pragma unroll
    for (int i = 0; i < 4; ++i) {   // 4 rounds x 256 threads x 16B = 16KB/tile
      gload_lds16(Ag0 + (size_t)i * 32 * Kd + kt, &As[i * 2048 + ldsb]);
      gload_lds16(Bg0 + (size_t)i * 32 * Kd + kt, &Bs[i * 2048 + ldsb]);
    }
    __syncthreads();               // drains DMA (vmcnt 0) + WAR protection
#pragma unroll
    for (int s = 0; s < 2; ++s) {
      bf16x8 af[4], bfr[4];
#pragma unroll
      for (int i = 0; i < 4; ++i) {
        const int m = wm * 64 + i * 16 + l16;
        af[i] = *(const bf16x8*)&As[m * 64 + (s * 4 + quad) * 8];
        const int n = wn * 64 + i * 16 + l16;
        bfr[i] = *(const bf16x8*)&Bs[n * 64 + (s * 4 + quad) * 8];
      }
#pragma unroll
      for (int i = 0; i < 4; ++i)
#pragma unroll
        for (int j = 0; j < 4; ++j)
          acc[i][j] = __builtin_amdgcn_mfma_f32_16x16x32_bf16(af[i], bfr[j],
                                                              acc[i][j], 0, 0, 0);
    }
    __syncthreads();
  }

#pragma unroll
  for (int i = 0; i < 4; ++i) {
    const int mbase = blockIdx.x * 128 + wm * 64 + i * 16 + quad * 4;
#pragma unroll
    for (int j = 0; j < 4; ++j) {
      const int nb = blockIdx.y * 128 + wn * 64 + j * 16;   // 16-aligned: never
      const int n = nb + l16;                               // crosses a 768 edge
      const float bv = bf2f(bias[n]);
      const int which = nb / 768;          // uniform per (block, wave, j)
      const int b = mbase >> 12, t = mbase & 4095;
      const int c = n - which * 768;
      const int h = c >> 6, d = c & 63;
      const size_t bh = (size_t)b * 12 + h;
      if (which == 0) {
#pragma unroll
        for (int r = 0; r < 4; ++r)
          O0[((bh * 4096 + t + r) << 6) + d] =
              f2bf((acc[i][j][r] + bv) * QSCALE);
      } else if (which == 1) {
#pragma unroll
        for (int r = 0; r < 4; ++r)
          O1[((bh * 4096 + t + r) << 6) + d] = f2bf(acc[i][j][r] + bv);
      } else {
        ushort4 pk;                        // V^T: 4 consecutive t -> one 8B store
        pk.x = f2bf(acc[i][j][0] + bv);
        pk.y = f2bf(acc[i][j][1] + bv);
        pk.z = f2bf(acc[i][j][2] + bv);
        pk.w = f2bf(acc[i][j][3] + bv);
        *(ushort4*)&O2[((bh << 6) + (size_t)d) * 4096 + t] = pk;
      }
    }
  }
}

// Output projection: tile 128(M) x 64(N), grid (64,12) = 768 blocks = 3/CU.
// 4 waves of 32x64; acc[2][4]; staging 4 A-rounds + 2 B-rounds of DMA.
__global__ __launch_bounds__(256, 3)
void gemm_n64(const u16* __restrict__ A, const u16* __restrict__ Bt,
              const u16* __restrict__ bias, float* __restrict__ out, int Kd) {
  __shared__ __align__(16) u16 As[128 * 64];
  __shared__ __align__(16) u16 Bs[64 * 64];
  const int tid = threadIdx.x;
  const int lane = tid & 63, wave = tid >> 6;
  const int l16 = lane & 15, quad = lane >> 4;

  const u16* Ag0 = A + (size_t)blockIdx.x * 128 * Kd +
                   (size_t)(tid >> 3) * Kd + (tid & 7) * 8;
  const u16* Bg0 = Bt + (size_t)blockIdx.y * 64 * Kd +
                   (size_t)(tid >> 3) * Kd + (tid & 7) * 8;
  const int ldsb = wave * 512;

  f32x4 acc[2][4] = {};
  for (int kt = 0; kt < Kd; kt += 64) {
#pragma unroll
    for (int i = 0; i < 4; ++i)
      gload_lds16(Ag0 + (size_t)i * 32 * Kd + kt, &As[i * 2048 + ldsb]);
#pragma unroll
    for (int i = 0; i < 2; ++i)
      gload_lds16(Bg0 + (size_t)i * 32 * Kd + kt, &Bs[i * 2048 + ldsb]);
    __syncthreads();
#pragma unroll
    for (int s = 0; s < 2; ++s) {
      bf16x8 af[2], bfr[4];
#pragma unroll
      for (int i = 0; i < 2; ++i) {
        const int m = wave * 32 + i * 16 + l16;
        af[i] = *(const bf16x8*)&As[m * 64 + (s * 4 + quad) * 8];
      }
#pragma unroll
      for (int j = 0; j < 4; ++j) {
        const int n = j * 16 + l16;
        bfr[j] = *(const bf16x8*)&Bs[n * 64 + (s * 4 + quad) * 8];
      }
#pragma unroll
      for (int i = 0; i < 2; ++i)
#pragma unroll
        for (int j = 0; j < 4; ++j)
          acc[i][j] = __builtin_amdgcn_mfma_f32_16x16x32_bf16(af[i], bfr[j],
                                                              acc[i][j], 0, 0, 0);
    }
    __syncthreads();
  }

#pragma unroll
  for (int i = 0; i < 2; ++i) {
    const int mbase = blockIdx.x * 128 + wave * 32 + i * 16 + quad * 4;
#pragma unroll
    for (int j = 0; j < 4; ++j) {
      const int n = blockIdx.y * 64 + j * 16 + l16;
      const float bv = bf2f(bias[n]);
#pragma unroll
      for (int r = 0; r < 4; ++r)
        out[(size_t)(mbase + r) * 768 + n] = acc[i][j][r] + bv;
    }
  }
}

// ---------------------------------------------------------------- attention
// Grid: 24 bh x 80 chunks = 1920 blocks. Chunk = (q-tile qt, j-th run of 16
// KV tiles). nc(qt)=ceil((qt+1)/8): qt<8 single-chunk -> direct Y write;
// else bf16 partial O + f32 partial l (additive; no-max softmax).
//
// LDS tiles are [64 rows][64 elems] LINEAR, data swizzled: element
// (row, c) of the logical tile lives at lds addr row*64 + (c ^ ((row&7)*8)).
// gload_lds writes base+lane*16 linearly; the per-lane GLOBAL src addr
// carries the inverse (same) XOR. All reads apply the XOR.
__global__ __launch_bounds__(256, 3)
void attn_chunk(const u16* __restrict__ Q, const u16* __restrict__ K,
                const u16* __restrict__ Vt, u16* __restrict__ Y,
                u16* __restrict__ part_o, float* __restrict__ part_l) {
  const int idx = blockIdx.x;
  const int bh = idx % 24;               // XCD-pinned
  const int cid = 79 - (idx / 24);       // big q-tiles dispatch first
  int qt = 0, base = 0, nc = 1;
  for (int q = 0; q < 32; ++q) {         // decode cid -> (qt, j)
    const int c = (q >> 3) + 1;
    if (cid < base + c) { qt = q; nc = c; break; }
    base += c;
  }
  const int j = cid - base;
  const int Nt = 2 * qt + 2;
  const int kbeg = j * 16;
  const int kend = (kbeg + 16 < Nt) ? kbeg + 16 : Nt;
  const int q0 = qt * 128;
  const int b = bh / 12, h = bh % 12;
  const size_t ho = (size_t)bh * 4096 * 64;
  const u16* Qg = Q + ho + (size_t)q0 * 64;
  const u16* Kg = K + ho;
  const u16* Vg = Vt + ho;               // (64, 4096)

  __shared__ __align__(16) u16 Ks[3][64 * 64];
  __shared__ __align__(16) u16 Vs[3][64 * 64];

  const int tid = threadIdx.x;
  const int lane = tid & 63, wave = tid >> 6;
  const int l16 = lane & 15, quad = lane >> 4;
  const int sw8 = (l16 & 7) * 8;         // read-side XOR (elems)

  // staging geometry: thread covers logical tile row rl=tid>>3, granule m=tid&7
  const int rl = tid >> 3, m7 = tid & 7;
  const int cs = (m7 ^ (rl & 7)) * 8;    // pre-swizzled source column (elems)
  const u16* kg0 = Kg + (size_t)rl * 64 + cs;     // + kt2*4096
  const u16* vg0 = Vg + (size_t)rl * 4096 + cs;   // + kt2*64
  const int wb = wave * 512;             // per-wave LDS base (elems)

  bf16x8 qf[2][2];
#pragma unroll
  for (int rt = 0; rt < 2; ++rt)
#pragma unroll
    for (int s = 0; s < 2; ++s)
      qf[rt][s] = *(const bf16x8*)&Qg[(wave * 32 + rt * 16 + l16) * 64 + s * 32 + quad * 8];

  bf16x8 ones;
#pragma unroll
  for (int e = 0; e < 8; ++e) ones[e] = (short)0x3F80;   // bf16 1.0

  f32x4 lacc[2] = {};
  f32x4 o[2][4] = {};

  auto stage = [&](int bf, int kt2) {
    const size_t ko = (size_t)kt2 * 4096;   // kt2*64 rows * 64 elems
    const int to = kt2 * 64;
    gload_lds16(kg0 + ko,               &Ks[bf][wb]);
    gload_lds16(kg0 + ko + 2048,        &Ks[bf][2048 + wb]);        // rows +32
    gload_lds16(vg0 + to,               &Vs[bf][wb]);
    gload_lds16(vg0 + to + 32 * 4096,   &Vs[bf][2048 + wb]);        // d rows +32
  };

  // ---- prologue: depth-2 prefetch, counted wait for buffer 0 ----
  const int ntt = kend - kbeg;
  stage(0, kbeg);
  if (ntt > 1) {
    stage(1, kbeg + 1);
    asm volatile("s_waitcnt vmcnt(4)" ::: "memory");   // buf0's 4 landed
  } else {
    asm volatile("s_waitcnt vmcnt(0)" ::: "memory");
  }
  __builtin_amdgcn_sched_barrier(0);
  __builtin_amdgcn_s_barrier();
  int cur = 0;

  for (int kt2 = kbeg; kt2 < kend; ++kt2) {
    const int t0 = kt2 * 64;
    const bool pf = (kt2 + 2 < kend);
    if (pf) {                            // depth-2 prefetch into 3rd buffer
      int nb = cur + 2; if (nb >= 3) nb -= 3;
      stage(nb, kt2 + 2);
    }
    __builtin_amdgcn_sched_barrier(0);   // keep DMA issue ahead of compute

    // ---- S^T = K Q^T : 16 MFMA. sc[nt][rt]: row=t (quad*4+r), col=q (l16)
    f32x4 sc[4][2] = {};
#pragma unroll
    for (int s = 0; s < 2; ++s) {
      bf16x8 kf[4];
#pragma unroll
      for (int nt = 0; nt < 4; ++nt)
        kf[nt] = *(const bf16x8*)&Ks[cur][(nt * 16 + l16) * 64 +
                                          ((s * 32 + quad * 8) ^ sw8)];
      __builtin_amdgcn_s_setprio(1);
#pragma unroll
      for (int nt = 0; nt < 4; ++nt)
#pragma unroll
        for (int rt = 0; rt < 2; ++rt)
          sc[nt][rt] = __builtin_amdgcn_mfma_f32_16x16x32_bf16(kf[nt], qf[rt][s],
                                                               sc[nt][rt], 0, 0, 0);
      __builtin_amdgcn_s_setprio(0);
    }

    // ---- no-max softmax + in-register bf16 pack (l via PV ones-col) ----
    u32 pw[4][2][2];
#pragma unroll
    for (int rt = 0; rt < 2; ++rt) {
      const int rowb = q0 + wave * 32 + rt * 16;
      if (t0 + 63 <= rowb) {               // tile fully below diagonal
#pragma unroll
        for (int nt = 0; nt < 4; ++nt) {
          f32x4 p;
#pragma unroll
          for (int r = 0; r < 4; ++r)
            p[r] = __builtin_amdgcn_exp2f(sc[nt][rt][r]);
          pw[nt][rt][0] = cvtpk(p[0], p[1]);
          pw[nt][rt][1] = cvtpk(p[2], p[3]);
        }
      } else {
        const int qrow = rowb + l16;
#pragma unroll
        for (int nt = 0; nt < 4; ++nt) {
          f32x4 p;
#pragma unroll
          for (int r = 0; r < 4; ++r) {
            float pv = __builtin_amdgcn_exp2f(sc[nt][rt][r]);
            if (t0 + nt * 16 + quad * 4 + r > qrow) pv = 0.f;
            p[r] = pv;
          }
          pw[nt][rt][0] = cvtpk(p[0], p[1]);
          pw[nt][rt][1] = cvtpk(p[2], p[3]);
        }
      }
    }

    // ---- O += P V (+ l += P 1) : 20 MFMA, permuted k-slots both operands
#pragma unroll
    for (int s2 = 0; s2 < 2; ++s2) {
      bf16x8 vf[4];
#pragma unroll
      for (int dt = 0; dt < 4; ++dt) {
        const int vbase = (dt * 16 + l16) * 64;
        const int a1 = vbase + ((s2 * 32 + quad * 4) ^ sw8);
        union { uint2 hv[2]; bf16x8 v; } uv;
        uv.hv[0] = *(const uint2*)&Vs[cur][a1];        // t' = 32*s2+quad*4+0..3
        uv.hv[1] = *(const uint2*)&Vs[cur][a1 ^ 16];   // t' = +16
        vf[dt] = uv.v;
      }
#pragma unroll
      for (int rt = 0; rt < 2; ++rt) {
        union { u32 w[4]; bf16x8 v; } up;
        up.w[0] = pw[2 * s2][rt][0];
        up.w[1] = pw[2 * s2][rt][1];
        up.w[2] = pw[2 * s2 + 1][rt][0];
        up.w[3] = pw[2 * s2 + 1][rt][1];
        __builtin_amdgcn_s_setprio(1);
#pragma unroll
        for (int dt = 0; dt < 4; ++dt)
          o[rt][dt] = __builtin_amdgcn_mfma_f32_16x16x32_bf16(up.v, vf[dt],
                                                              o[rt][dt], 0, 0, 0);
        lacc[rt] = __builtin_amdgcn_mfma_f32_16x16x32_bf16(up.v, ones,
                                                           lacc[rt], 0, 0, 0);
        __builtin_amdgcn_s_setprio(0);
      }
    }

    if (kt2 + 1 < kend) {
      // counted wait: leave k+2's 4 DMAs in flight, require k+1's landed.
      if (pf) asm volatile("s_waitcnt vmcnt(4)" ::: "memory");
      else    asm volatile("s_waitcnt vmcnt(0)" ::: "memory");
      __builtin_amdgcn_sched_barrier(0);
      __builtin_amdgcn_s_barrier();
      if (++cur == 3) cur = 0;
    }
  }

  // lacc[rt][r] = l for q-row (quad*4+r), identical across lanes: no shuffles.
  if (nc == 1) {
    // direct: Y (b, t, h*64+d) bf16
#pragma unroll
    for (int rt = 0; rt < 2; ++rt)
#pragma unroll
      for (int r = 0; r < 4; ++r) {
        const float inv = 1.f / lacc[rt][r];
        const int t = q0 + wave * 32 + rt * 16 + quad * 4 + r;
#pragma unroll
        for (int dt = 0; dt < 4; ++dt)
          Y[((size_t)b * 4096 + t) * 768 + h * 64 + dt * 16 + l16] =
              f2bf(o[rt][dt][r] * inv);
      }
  } else {
    const int pslot = bh * 72 + (cid - 8);     // cids 8..79 are partial chunks
    u16* po = part_o + (size_t)pslot * 8192;   // [row 0..127][d 0..63]
    float* pl = part_l + pslot * 128;
#pragma unroll
    for (int rt = 0; rt < 2; ++rt)
#pragma unroll
      for (int r = 0; r < 4; ++r) {
        const int row = wave * 32 + rt * 16 + quad * 4 + r;
#pragma unroll
        for (int dt = 0; dt < 4; ++dt)
          po[row * 64 + dt * 16 + l16] = f2bf(o[rt][dt][r]);
        if (l16 == 0) pl[row] = lacc[rt][r];
      }
  }
}

// Combine partial chunks for qt >= 8.  Grid (24 bh, 24 qt-8).
// R22: vectorized — one uint4 (8 bf16) per chunk per row-group instead of
// scalar 2B loads; 4 unrolled groups/thread for ILP; 16B packed Y store.
__global__ __launch_bounds__(256, 8)
void attn_combine(const u16* __restrict__ part_o, const float* __restrict__ part_l,
                  u16* __restrict__ Y) {
  const int bh = blockIdx.x, qt = 8 + blockIdx.y;
  const int g = qt >> 3, i = qt & 7;
  const int nc = g + 1;
  const int base = 4 * g * (g + 1) + i * (g + 1);
  const int slot0 = bh * 72 + base - 8;
  const int b = bh / 12, h = bh % 12;
  const int q0 = qt * 128;
  const int tid = threadIdx.x;
  // 8192 elems = 1024 groups of 8 contiguous d; 256 threads -> 4 groups each.
#pragma unroll
  for (int gi = 0; gi < 4; ++gi) {
    const int gix = gi * 256 + tid;
    const int row = gix >> 3, d0 = (gix & 7) * 8;
    float acc[8] = {};
    float ls = 0.f;
    for (int c = 0; c < nc; ++c) {
      const uint4 v = *(const uint4*)&part_o[(size_t)(slot0 + c) * 8192 +
                                             row * 64 + d0];
      const u16* pv = (const u16*)&v;
#pragma unroll
      for (int k = 0; k < 8; ++k) acc[k] += bf2f(pv[k]);
      ls += part_l[(slot0 + c) * 128 + row];
    }
    const float inv = 1.f / ls;
    uint4 ov;
    ov.x = cvtpk(acc[0] * inv, acc[1] * inv);
    ov.y = cvtpk(acc[2] * inv, acc[3] * inv);
    ov.z = cvtpk(acc[4] * inv, acc[5] * inv);
    ov.w = cvtpk(acc[6] * inv, acc[7] * inv);
    *(uint4*)&Y[((size_t)b * 4096 + q0 + row) * 768 + h * 64 + d0] = ov;
  }
}

// ---------------------------------------------------------------- launch
extern "C" void kernel_launch(void* const* d_in, const int* in_sizes, int n_in,
                              void* d_out, int out_size, void* d_ws, size_t ws_size,
                              hipStream_t stream) {
  (void)in_sizes; (void)n_in;
  const float* x      = (const float*)d_in[0];
  const float* w_attn = (const float*)d_in[1];
  const float* b_attn = (const float*)d_in[2];
  const float* w_proj = (const float*)d_in[3];
  const float* b_proj = (const float*)d_in[4];
  float* out = (float*)d_out;

  char* ws = (char*)d_ws;
  size_t off = 0;
  auto alloc = [&](size_t bytes) -> void* {
    void* p = ws + off;
    off += (bytes + 255) & ~(size_t)255;
    return p;
  };
  u16* xb  = (u16*)alloc((size_t)8192 * 768 * 2);
  u16* WtA = (u16*)alloc((size_t)2304 * 768 * 2);
  u16* WtP = (u16*)alloc((size_t)768 * 768 * 2);
  u16* ba  = (u16*)alloc(2304 * 2);
  u16* bp  = (u16*)alloc(768 * 2);
  u16* Q   = (u16*)alloc((size_t)6291456 * 2);   // (B,H,T,64), pre-scaled
  u16* Kp  = (u16*)alloc((size_t)6291456 * 2);   // (B,H,T,64)
  u16* Vt  = (u16*)alloc((size_t)6291456 * 2);   // (B,H,64,T)
  u16* Y   = (u16*)alloc((size_t)6291456 * 2);
  u16* part_o  = (u16*)alloc((size_t)24 * 72 * 8192 * 2);   // 28.3 MB
  float* part_l = (float*)alloc((size_t)24 * 72 * 128 * 4);

  if (ws_size < off) {   // decodable sentinel: absmax ~= 100 + ws_MB
    fill_sentinel_f32<<<256, 256, 0, stream>>>(out, out_size,
                                               100.0f + (float)(ws_size >> 20));
    return;
  }

  prep<<<3329, 256, 0, stream>>>(x, w_attn, b_attn, w_proj, b_proj,
                                 xb, WtA, WtP, ba, bp);
  gemm128<<<dim3(64, 18), 256, 0, stream>>>(xb, WtA, ba, Q, Kp, Vt, 768);
  attn_chunk<<<1920, 256, 0, stream>>>(Q, Kp, Vt, Y, part_o, part_l);
  attn_combine<<<dim3(24, 24), 256, 0, stream>>>(part_o, part_l, Y);
  gemm_n64<<<dim3(64, 12), 256, 0, stream>>>(Y, WtP, bp, out, 768);
}